// Round 1
// baseline (363.544 us; speedup 1.0000x reference)
//
#include <hip/hip_runtime.h>

// AttributeDecoder: gather K*S rows (D=256) from features (N,D), per-head
// GEMM (D=256 -> V=8) + bias. fp32 in/out.
// Strategy: wave-per-s. One global_load_dwordx4 per s = one full 1KB row,
// perfectly coalesced. W slice (4 d-rows x 8 v) lives in registers per lane.
// Butterfly reduce 8 accumulators across 64 lanes, cndmask-select, store.

#define KH 24
#define SS 16384
#define VV 8
#define DD 256

__global__ __launch_bounds__(256) void attr_decoder_kernel(
    const float* __restrict__ feats,      // (N, 256)
    const int*   __restrict__ mask_idx,   // (K, S)
    const float* __restrict__ head_w,     // (K, 256, 8)
    const float* __restrict__ head_b,     // (K, 8)
    float*       __restrict__ out)        // (K, S, 8)
{
    const int lane  = threadIdx.x & 63;
    const int wv    = threadIdx.x >> 6;       // wave in block (0..3)
    const int k     = blockIdx.x >> 6;        // 64 blocks per head
    const int chunk = blockIdx.x & 63;

    // Per-lane register W slice: d = lane*4 + t, t = 0..3, all 8 v's.
    // W row (8 floats = 32B) loaded as two float4; lane*32-float offset => 128B aligned.
    const float* Wk = head_w + (size_t)k * (DD * VV);
    float w[4][8];
    #pragma unroll
    for (int t = 0; t < 4; ++t) {
        const float4 a = *(const float4*)(Wk + (lane * 4 + t) * VV);
        const float4 b = *(const float4*)(Wk + (lane * 4 + t) * VV + 4);
        w[t][0] = a.x; w[t][1] = a.y; w[t][2] = a.z; w[t][3] = a.w;
        w[t][4] = b.x; w[t][5] = b.y; w[t][6] = b.z; w[t][7] = b.w;
    }
    const float bias = head_b[k * VV + (lane & 7)];

    const float4* feats4 = (const float4*)feats;
    const int s_base = chunk * 256 + wv * 64;          // 64 s per wave
    const int* mi = mask_idx + k * SS + s_base;
    float* outp = out + ((size_t)k * SS + s_base) * VV;

    for (int i = 0; i < 64; ++i) {
        const int row = mi[i];                          // wave-uniform
        const float4 f = feats4[(size_t)row * 64 + lane]; // coalesced 1KB row

        float acc[8];
        #pragma unroll
        for (int v = 0; v < 8; ++v) {
            acc[v] = f.x * w[0][v];
            acc[v] = fmaf(f.y, w[1][v], acc[v]);
            acc[v] = fmaf(f.z, w[2][v], acc[v]);
            acc[v] = fmaf(f.w, w[3][v], acc[v]);
        }

        // Reduce each of the 8 accumulators across all 64 lanes.
        #pragma unroll
        for (int m = 1; m < 64; m <<= 1) {
            #pragma unroll
            for (int v = 0; v < 8; ++v)
                acc[v] += __shfl_xor(acc[v], m, 64);
        }

        // Every lane now holds all 8 totals; select acc[lane&7] without
        // runtime array indexing (7 cndmasks).
        const float r0 = (lane & 1) ? acc[1] : acc[0];
        const float r1 = (lane & 1) ? acc[3] : acc[2];
        const float r2 = (lane & 1) ? acc[5] : acc[4];
        const float r3 = (lane & 1) ? acc[7] : acc[6];
        const float q0 = (lane & 2) ? r1 : r0;
        const float q1 = (lane & 2) ? r3 : r2;
        const float res = ((lane & 4) ? q1 : q0) + bias;

        if (lane < 8) outp[i * VV + lane] = res;        // 32B per s
    }
}

extern "C" void kernel_launch(void* const* d_in, const int* in_sizes, int n_in,
                              void* d_out, int out_size, void* d_ws, size_t ws_size,
                              hipStream_t stream) {
    // d_in[0] = block_type_grid (unused by reference)
    const float* feats    = (const float*)d_in[1];
    const int*   mask_idx = (const int*)  d_in[2];
    const float* head_w   = (const float*)d_in[3];
    const float* head_b   = (const float*)d_in[4];
    float* out = (float*)d_out;

    dim3 grid(KH * 64);   // 24 heads * 64 chunks; 256 s per block
    dim3 block(256);
    attr_decoder_kernel<<<grid, block, 0, stream>>>(feats, mask_idx, head_w, head_b, out);
}

// Round 2
// 230.541 us; speedup vs baseline: 1.5769x; 1.5769x over previous
//
#include <hip/hip_runtime.h>

// AttributeDecoder: gather K*S rows (D=256) from features (N,256), per-head
// Linear 256->8 + bias. fp32.
// R2: wave-per-s kept (coalesced 1KB row gather), but the 64-lane x 8-value
// reduction is restructured as a split-butterfly: rounds on v-bits select the
// half each lane keeps (values 8->4->2->1), so total exchanged words per s is
// 4+2+1+1+1+1 = 10 instead of 48. Exact-xor rounds 1,2,8 run on the VALU via
// DPP (quad_perm 0xB1/0x4E, row_ror:8) -> only xor4/16/32 touch the DS pipe
// (3 DS ops/s vs 48). 4-s unroll: 4 gathers in flight, one 128B store per 4 s.

#define KH 24
#define SS 16384
#define VV 8
#define DD 256

template <int CTRL>
__device__ __forceinline__ float dpp_mov(float x) {
    int xi = __builtin_bit_cast(int, x);
    int r = __builtin_amdgcn_update_dpp(xi, xi, CTRL, 0xF, 0xF, false);
    return __builtin_bit_cast(float, r);
}

// acc[v] = this lane's partial for logits v (v=0..7), summed over its 4 d's.
// Returns: full sum for v = lane&7 (identical across the 8 lane-groups).
__device__ __forceinline__ float reduce8(const float acc[8], int lane) {
    const bool b0 = lane & 1;
    const bool b1 = lane & 2;
    const bool b2 = lane & 4;

    // Round 1: xor1 (DPP quad_perm [1,0,3,2]). Keep v's with v&1 == b0.
    float a4[4];
#pragma unroll
    for (int j = 0; j < 4; ++j) {
        const float keep = b0 ? acc[2 * j + 1] : acc[2 * j];
        const float send = b0 ? acc[2 * j] : acc[2 * j + 1];
        a4[j] = keep + dpp_mov<0xB1>(send);     // a4[j]: v = 2j + b0
    }
    // Round 2: xor2 (DPP quad_perm [2,3,0,1]). v bit1 of a4[j] is j&1.
    float a2[2];
#pragma unroll
    for (int m = 0; m < 2; ++m) {
        const float keep = b1 ? a4[2 * m + 1] : a4[2 * m];
        const float send = b1 ? a4[2 * m] : a4[2 * m + 1];
        a2[m] = keep + dpp_mov<0x4E>(send);     // a2[m]: v = 4m + 2*b1 + b0
    }
    // Round 3: xor4 (DS). v bit2 of a2[m] is m.
    {
        const float keep = b2 ? a2[1] : a2[0];
        const float send = b2 ? a2[0] : a2[1];
        float a1 = keep + __shfl_xor(send, 4, 64);   // v = lane&7
        // Plain rounds over lane bits 3,4,5.
        a1 += dpp_mov<0x128>(a1);                    // row_ror:8 == xor8
        a1 += __shfl_xor(a1, 16, 64);
        a1 += __shfl_xor(a1, 32, 64);
        return a1;
    }
}

__global__ __launch_bounds__(256) void attr_decoder_kernel(
    const float* __restrict__ feats,      // (131072, 256)
    const int*   __restrict__ mask_idx,   // (24, 16384)
    const float* __restrict__ head_w,     // (24, 256, 8)
    const float* __restrict__ head_b,     // (24, 8)
    float*       __restrict__ out)        // (24, 16384, 8)
{
    const int lane  = threadIdx.x & 63;
    const int wv    = threadIdx.x >> 6;        // 0..3
    const int k     = blockIdx.x >> 7;         // 128 chunks per head
    const int chunk = blockIdx.x & 127;

    // Register W slice: d = lane*4 + t, all 8 v.
    const float* Wk = head_w + (size_t)k * (DD * VV);
    float w[4][8];
#pragma unroll
    for (int t = 0; t < 4; ++t) {
        const float4 a = *(const float4*)(Wk + (lane * 4 + t) * VV);
        const float4 b = *(const float4*)(Wk + (lane * 4 + t) * VV + 4);
        w[t][0] = a.x; w[t][1] = a.y; w[t][2] = a.z; w[t][3] = a.w;
        w[t][4] = b.x; w[t][5] = b.y; w[t][6] = b.z; w[t][7] = b.w;
    }
    const float bias = head_b[k * VV + (lane & 7)];

    const float4* feats4 = (const float4*)feats;
    const int s_base = chunk * 128 + wv * 32;          // 32 s per wave
    const int* mi = mask_idx + k * SS + s_base;
    float* outp = out + ((size_t)k * SS + s_base) * VV;

    const int g = (lane >> 3) & 3;     // which of the 4 unrolled s this lane stores

    for (int i = 0; i < 32; i += 4) {
        const int4 rows = *(const int4*)(mi + i);      // wave-uniform 16B
        const float4 f0 = feats4[(size_t)rows.x * 64 + lane];
        const float4 f1 = feats4[(size_t)rows.y * 64 + lane];
        const float4 f2 = feats4[(size_t)rows.z * 64 + lane];
        const float4 f3 = feats4[(size_t)rows.w * 64 + lane];

        float r[4];
        const float4 f[4] = {f0, f1, f2, f3};
#pragma unroll
        for (int u = 0; u < 4; ++u) {
            float acc[8];
#pragma unroll
            for (int v = 0; v < 8; ++v) {
                acc[v] = f[u].x * w[0][v];
                acc[v] = fmaf(f[u].y, w[1][v], acc[v]);
                acc[v] = fmaf(f[u].z, w[2][v], acc[v]);
                acc[v] = fmaf(f[u].w, w[3][v], acc[v]);
            }
            r[u] = reduce8(acc, lane);
        }

        // lanes 0..31 store 4 s at once (128B contiguous): s = i + (lane>>3), v = lane&7
        const float r01 = (g & 1) ? r[1] : r[0];
        const float r23 = (g & 1) ? r[3] : r[2];
        const float val = ((g & 2) ? r23 : r01) + bias;
        if (lane < 32) outp[i * VV + lane] = val;
    }
}

extern "C" void kernel_launch(void* const* d_in, const int* in_sizes, int n_in,
                              void* d_out, int out_size, void* d_ws, size_t ws_size,
                              hipStream_t stream) {
    // d_in[0] = block_type_grid (unused by reference)
    const float* feats    = (const float*)d_in[1];
    const int*   mask_idx = (const int*)  d_in[2];
    const float* head_w   = (const float*)d_in[3];
    const float* head_b   = (const float*)d_in[4];
    float* out = (float*)d_out;

    dim3 grid(KH * 128);   // 24 heads * 128 chunks; 128 s per block
    dim3 block(256);
    attr_decoder_kernel<<<grid, block, 0, stream>>>(feats, mask_idx, head_w, head_b, out);
}